// Round 9
// baseline (548.844 us; speedup 1.0000x reference)
//
#include <hip/hip_runtime.h>
#include <cstdint>

// ---- physics constants (match reference) ----
#define WATER_DENSITY 1000.0f
#define ICE_DENSITY 917.0f
#define GRAVITY 9.81f
#define TILL_FRICTION 0.6f
#define LATENT_HEAT 3.34e5f
#define ICE_FLUIDITY 6e-24f
#define WATER_VISCOSITY 1.787e-3f
#define FLOW_REGIME_SCALAR 1e-3f
#define MIN_EFFECTIVE_PRESSURE 1e4f

// Packed u64 accumulator for (degree, sum of u_slide):
//   bits 48..63 : link-endpoint count
//   bits  0..47 : sum of (round(u * 2^46) + 2^40) per endpoint
#define U_SCALE      7.0368744177664e13f     /* 2^46 */
#define U_INV_SCALE  1.4210854715202004e-14f /* 2^-46 */
#define U_BIAS       (1LL << 40)
#define CNT_ONE      (1ULL << 48)
#define LOW_MASK     0xFFFFFFFFFFFFULL

__device__ __forceinline__ bool load_bnd(const uint8_t* p, int i, int is_u8) {
    if (is_u8) return p[i] != 0;
    return ((const int*)p)[i] != 0;
}

// Pass 1: per-link, ONE packed u64 atomic per endpoint (count + u fixed-point).
// Block 0 additionally detects the boundary-flag encoding over the first
// 64 KB: any nonzero byte at offset %4 != 0 => byte-wise bool (int32 0/1
// little-endian is nonzero only at %4==0). ~2400 expected hits if byte-wise.
__global__ void link_accum_kernel(const int* __restrict__ tail,
                                  const int* __restrict__ head,
                                  const float* __restrict__ u,
                                  unsigned long long* __restrict__ pack,
                                  const uint8_t* __restrict__ bnd_raw,
                                  int* __restrict__ flag_u8,
                                  int n_scan,
                                  int n_links) {
    if (blockIdx.x == 0) {
        for (int j = threadIdx.x; j < n_scan; j += blockDim.x) {
            if ((j & 3) != 0 && bnd_raw[j] != 0) { *flag_u8 = 1; break; }
        }
    }
    int i = blockIdx.x * blockDim.x + threadIdx.x;
    if (i < n_links) {
        int t = tail[i];
        int h = head[i];
        long long fixed = llrintf(u[i] * U_SCALE);
        unsigned long long c = CNT_ONE + (unsigned long long)(fixed + U_BIAS);
        atomicAdd(&pack[t], c);
        atomicAdd(&pack[h], c);
    }
}

// Pass 2: per-node midpoint math. Reads pack[i] (u64) and writes hc[i]
// (float2 {h, conduit}) — same 8-byte slot, element-wise read-then-write
// within one thread, so the aliasing is safe. Also writes mc.
__global__ void node_mid_kernel(const float* __restrict__ head_in,
                                const float* __restrict__ bedrock,
                                const float* __restrict__ overburden,
                                const float* __restrict__ geo,
                                const uint8_t* __restrict__ bnd_raw,
                                const int* __restrict__ flag_u8,
                                unsigned long long* pack_hc,  // no restrict: aliased
                                float* __restrict__ mc_out,
                                int n_nodes) {
    const int is_u8 = *flag_u8;
    float2* hc = (float2*)pack_hc;
    int i = blockIdx.x * blockDim.x + threadIdx.x;
    if (i >= n_nodes) return;

    float bed = bedrock[i];
    float ob  = overburden[i];
    float h   = load_bnd(bnd_raw, i, is_u8) ? bed : head_in[i];

    float wp = WATER_DENSITY * GRAVITY * (h - bed);
    float N  = ob - wp;
    N = (N > ob) ? ob : N;
    N = (N < MIN_EFFECTIVE_PRESSURE) ? MIN_EFFECTIVE_PRESSURE : N;

    unsigned long long v = pack_hc[i];
    long long cnt_i = (long long)(v >> 48);
    long long sumfix = (long long)(v & LOW_MASK) - cnt_i * U_BIAS;
    float u_sum = (float)sumfix * U_INV_SCALE;
    float d = (float)cnt_i;
    d = (d > 1.0f) ? d : 1.0f;
    float u_node = u_sum / d;

    float friction  = fabsf(u_node * (TILL_FRICTION * N));
    float melt_flux = (geo[i] + friction) / LATENT_HEAT;

    float N3 = N * N * N;
    float conduit = melt_flux / ICE_DENSITY / (ICE_FLUIDITY * N3);

    float melt_term    = melt_flux * (1.0f / WATER_DENSITY - 1.0f / ICE_DENSITY);
    float closure_term = ICE_FLUIDITY * N3 * conduit;

    hc[i]     = make_float2(h, conduit);
    mc_out[i] = melt_term + closure_term;
}

// Pass 3: per-link flux. ONE float2 gather per endpoint, scatter signed flux.
__global__ void link_flux_kernel(const int* __restrict__ tail,
                                 const int* __restrict__ head,
                                 const float* __restrict__ len,
                                 const float* __restrict__ Re,
                                 const float2* __restrict__ hc,
                                 float* __restrict__ net,
                                 int n_links) {
    int i = blockIdx.x * blockDim.x + threadIdx.x;
    if (i >= n_links) return;
    int t  = tail[i];
    int hd = head[i];
    float L = len[i];
    float2 a = hc[t];
    float2 b = hc[hd];
    float grad = (b.x - a.x) / L;
    float cl = 0.5f * (a.y + b.y);
    float trans = (cl * cl * cl) * GRAVITY /
                  (12.0f * WATER_VISCOSITY * (1.0f + FLOW_REGIME_SCALAR * Re[i]));
    float flux = -trans * grad * L;
    atomicAdd(&net[t], flux);
    atomicAdd(&net[hd], -flux);
}

// Pass 4: finalize output.
__global__ void node_final_kernel(const uint8_t* __restrict__ bnd_raw,
                                  const int* __restrict__ flag_u8,
                                  const float* __restrict__ net,
                                  const float* __restrict__ area,
                                  const float* __restrict__ mc,
                                  float* __restrict__ out,
                                  int n_nodes) {
    const int is_u8 = *flag_u8;
    int i = blockIdx.x * blockDim.x + threadIdx.x;
    if (i >= n_nodes) return;
    float elliptic = load_bnd(bnd_raw, i, is_u8) ? 0.0f : (net[i] / area[i]);
    out[i] = elliptic - mc[i];
}

extern "C" void kernel_launch(void* const* d_in, const int* in_sizes, int n_in,
                              void* d_out, int out_size, void* d_ws, size_t ws_size,
                              hipStream_t stream) {
    const float*   head_in    = (const float*)d_in[0];
    const float*   Re         = (const float*)d_in[1];
    const float*   len        = (const float*)d_in[2];
    const float*   area       = (const float*)d_in[3];
    const float*   bedrock    = (const float*)d_in[4];
    const float*   overburden = (const float*)d_in[5];
    const float*   geo        = (const float*)d_in[6];
    const float*   u_slide    = (const float*)d_in[7];
    const int*     link_tail  = (const int*)d_in[8];
    const int*     link_head  = (const int*)d_in[9];
    const uint8_t* bnd_raw    = (const uint8_t*)d_in[10];

    const int n_nodes = in_sizes[0];
    const int n_links = in_sizes[1];

    // layout (float units): [pack/hc: 2n (u64 then float2, aliased) | net: n |
    //                        flag: 1 (+pad 256) | mc: n]  => ~16 MB total
    float* ws = (float*)d_ws;
    unsigned long long* pack = (unsigned long long*)ws;
    float2* hc     = (float2*)ws;
    float* net     = ws + 2 * (size_t)n_nodes;
    int*   flag    = (int*)(ws + 3 * (size_t)n_nodes);
    float* mc      = ws + 3 * (size_t)n_nodes + 256;

    // zero pack + net + flag in one contiguous async memset
    hipMemsetAsync(pack, 0, (3 * (size_t)n_nodes + 256) * sizeof(float), stream);

    const int BLK = 256;
    int grid_links = (n_links + BLK - 1) / BLK;   // uncapped: 1 link/thread
    int grid_nodes = (n_nodes + BLK - 1) / BLK;   // uncapped: 1 node/thread
    int n_scan = n_nodes < 65536 ? n_nodes : 65536;

    link_accum_kernel<<<grid_links, BLK, 0, stream>>>(link_tail, link_head, u_slide,
                                                      pack, bnd_raw, flag, n_scan,
                                                      n_links);
    node_mid_kernel<<<grid_nodes, BLK, 0, stream>>>(head_in, bedrock, overburden, geo,
                                                    bnd_raw, flag, pack, mc, n_nodes);
    link_flux_kernel<<<grid_links, BLK, 0, stream>>>(link_tail, link_head, len, Re,
                                                     hc, net, n_links);
    node_final_kernel<<<grid_nodes, BLK, 0, stream>>>(bnd_raw, flag, net, area, mc,
                                                      (float*)d_out, n_nodes);
}

// Round 10
// 532.941 us; speedup vs baseline: 1.0298x; 1.0298x over previous
//
#include <hip/hip_runtime.h>
#include <cstdint>

// ---- physics constants (match reference) ----
#define WATER_DENSITY 1000.0f
#define ICE_DENSITY 917.0f
#define GRAVITY 9.81f
#define TILL_FRICTION 0.6f
#define LATENT_HEAT 3.34e5f
#define ICE_FLUIDITY 6e-24f
#define WATER_VISCOSITY 1.787e-3f
#define FLOW_REGIME_SCALAR 1e-3f
#define MIN_EFFECTIVE_PRESSURE 1e4f

// Packed u64 accumulator for (degree, sum of u_slide):
//   bits 48..63 : link-endpoint count
//   bits  0..47 : sum of (round(u * 2^46) + 2^40) per endpoint
#define U_SCALE      7.0368744177664e13f     /* 2^46 */
#define U_INV_SCALE  1.4210854715202004e-14f /* 2^-46 */
#define U_BIAS       (1LL << 40)
#define CNT_ONE      (1ULL << 48)
#define LOW_MASK     0xFFFFFFFFFFFFULL

__device__ __forceinline__ bool load_bnd(const uint8_t* p, int i, int is_u8) {
    if (is_u8) return p[i] != 0;
    return ((const int*)p)[i] != 0;
}

// Pass 1: per-link, ONE packed u64 atomic per endpoint (count + u fixed-point).
// Grid-stride (capped blocks): ~4 links/thread gives each wave 8 independent
// atomics in flight and 4x fewer waves than 1-link/thread (r9 regression:
// per-wave launch+drain overhead cost ~35us).
// Block 0 additionally detects the boundary-flag encoding over the first
// 64 KB: any nonzero byte at offset %4 != 0 => byte-wise bool (int32 0/1
// little-endian is nonzero only at %4==0).
__global__ void link_accum_kernel(const int* __restrict__ tail,
                                  const int* __restrict__ head,
                                  const float* __restrict__ u,
                                  unsigned long long* __restrict__ pack,
                                  const uint8_t* __restrict__ bnd_raw,
                                  int* __restrict__ flag_u8,
                                  int n_scan,
                                  int n_links) {
    if (blockIdx.x == 0) {
        for (int j = threadIdx.x; j < n_scan; j += blockDim.x) {
            if ((j & 3) != 0 && bnd_raw[j] != 0) { *flag_u8 = 1; break; }
        }
    }
    int i = blockIdx.x * blockDim.x + threadIdx.x;
    int stride = gridDim.x * blockDim.x;
    for (; i < n_links; i += stride) {
        int t = tail[i];
        int h = head[i];
        long long fixed = llrintf(u[i] * U_SCALE);
        unsigned long long c = CNT_ONE + (unsigned long long)(fixed + U_BIAS);
        atomicAdd(&pack[t], c);
        atomicAdd(&pack[h], c);
    }
}

// Pass 2: per-node midpoint math. Reads pack[i] (u64) and writes hc[i]
// (float2 {h, conduit}) — same 8-byte slot, element-wise read-then-write
// within one thread, so the aliasing is safe. Also writes mc.
__global__ void node_mid_kernel(const float* __restrict__ head_in,
                                const float* __restrict__ bedrock,
                                const float* __restrict__ overburden,
                                const float* __restrict__ geo,
                                const uint8_t* __restrict__ bnd_raw,
                                const int* __restrict__ flag_u8,
                                unsigned long long* pack_hc,  // no restrict: aliased
                                float* __restrict__ mc_out,
                                int n_nodes) {
    const int is_u8 = *flag_u8;
    float2* hc = (float2*)pack_hc;
    int i = blockIdx.x * blockDim.x + threadIdx.x;
    int stride = gridDim.x * blockDim.x;
    for (; i < n_nodes; i += stride) {
        float bed = bedrock[i];
        float ob  = overburden[i];
        float h   = load_bnd(bnd_raw, i, is_u8) ? bed : head_in[i];

        float wp = WATER_DENSITY * GRAVITY * (h - bed);
        float N  = ob - wp;
        N = (N > ob) ? ob : N;
        N = (N < MIN_EFFECTIVE_PRESSURE) ? MIN_EFFECTIVE_PRESSURE : N;

        unsigned long long v = pack_hc[i];
        long long cnt_i = (long long)(v >> 48);
        long long sumfix = (long long)(v & LOW_MASK) - cnt_i * U_BIAS;
        float u_sum = (float)sumfix * U_INV_SCALE;
        float d = (float)cnt_i;
        d = (d > 1.0f) ? d : 1.0f;
        float u_node = u_sum / d;

        float friction  = fabsf(u_node * (TILL_FRICTION * N));
        float melt_flux = (geo[i] + friction) / LATENT_HEAT;

        float N3 = N * N * N;
        float conduit = melt_flux / ICE_DENSITY / (ICE_FLUIDITY * N3);

        float melt_term    = melt_flux * (1.0f / WATER_DENSITY - 1.0f / ICE_DENSITY);
        float closure_term = ICE_FLUIDITY * N3 * conduit;

        hc[i]     = make_float2(h, conduit);
        mc_out[i] = melt_term + closure_term;
    }
}

// Pass 3: per-link flux. ONE float2 gather per endpoint, scatter signed flux.
__global__ void link_flux_kernel(const int* __restrict__ tail,
                                 const int* __restrict__ head,
                                 const float* __restrict__ len,
                                 const float* __restrict__ Re,
                                 const float2* __restrict__ hc,
                                 float* __restrict__ net,
                                 int n_links) {
    int i = blockIdx.x * blockDim.x + threadIdx.x;
    int stride = gridDim.x * blockDim.x;
    for (; i < n_links; i += stride) {
        int t  = tail[i];
        int hd = head[i];
        float L = len[i];
        float2 a = hc[t];
        float2 b = hc[hd];
        float grad = (b.x - a.x) / L;
        float cl = 0.5f * (a.y + b.y);
        float trans = (cl * cl * cl) * GRAVITY /
                      (12.0f * WATER_VISCOSITY * (1.0f + FLOW_REGIME_SCALAR * Re[i]));
        float flux = -trans * grad * L;
        atomicAdd(&net[t], flux);
        atomicAdd(&net[hd], -flux);
    }
}

// Pass 4: finalize output.
__global__ void node_final_kernel(const uint8_t* __restrict__ bnd_raw,
                                  const int* __restrict__ flag_u8,
                                  const float* __restrict__ net,
                                  const float* __restrict__ area,
                                  const float* __restrict__ mc,
                                  float* __restrict__ out,
                                  int n_nodes) {
    const int is_u8 = *flag_u8;
    int i = blockIdx.x * blockDim.x + threadIdx.x;
    int stride = gridDim.x * blockDim.x;
    for (; i < n_nodes; i += stride) {
        float elliptic = load_bnd(bnd_raw, i, is_u8) ? 0.0f : (net[i] / area[i]);
        out[i] = elliptic - mc[i];
    }
}

extern "C" void kernel_launch(void* const* d_in, const int* in_sizes, int n_in,
                              void* d_out, int out_size, void* d_ws, size_t ws_size,
                              hipStream_t stream) {
    const float*   head_in    = (const float*)d_in[0];
    const float*   Re         = (const float*)d_in[1];
    const float*   len        = (const float*)d_in[2];
    const float*   area       = (const float*)d_in[3];
    const float*   bedrock    = (const float*)d_in[4];
    const float*   overburden = (const float*)d_in[5];
    const float*   geo        = (const float*)d_in[6];
    const float*   u_slide    = (const float*)d_in[7];
    const int*     link_tail  = (const int*)d_in[8];
    const int*     link_head  = (const int*)d_in[9];
    const uint8_t* bnd_raw    = (const uint8_t*)d_in[10];

    const int n_nodes = in_sizes[0];
    const int n_links = in_sizes[1];

    // layout (float units): [pack/hc: 2n (u64 then float2, aliased) | net: n |
    //                        flag: 1 (+pad 256) | mc: n]  => ~16 MB total
    float* ws = (float*)d_ws;
    unsigned long long* pack = (unsigned long long*)ws;
    float2* hc     = (float2*)ws;
    float* net     = ws + 2 * (size_t)n_nodes;
    int*   flag    = (int*)(ws + 3 * (size_t)n_nodes);
    float* mc      = ws + 3 * (size_t)n_nodes + 256;

    // zero pack + net + flag in one contiguous async memset
    hipMemsetAsync(pack, 0, (3 * (size_t)n_nodes + 256) * sizeof(float), stream);

    const int BLK = 256;
    int grid_links = (n_links + BLK - 1) / BLK;
    if (grid_links > 2048) grid_links = 2048;   // grid-stride: ~4 links/thread
    int grid_nodes = (n_nodes + BLK - 1) / BLK;
    if (grid_nodes > 2048) grid_nodes = 2048;   // grid-stride: ~2 nodes/thread
    int n_scan = n_nodes < 65536 ? n_nodes : 65536;

    link_accum_kernel<<<grid_links, BLK, 0, stream>>>(link_tail, link_head, u_slide,
                                                      pack, bnd_raw, flag, n_scan,
                                                      n_links);
    node_mid_kernel<<<grid_nodes, BLK, 0, stream>>>(head_in, bedrock, overburden, geo,
                                                    bnd_raw, flag, pack, mc, n_nodes);
    link_flux_kernel<<<grid_links, BLK, 0, stream>>>(link_tail, link_head, len, Re,
                                                     hc, net, n_links);
    node_final_kernel<<<grid_nodes, BLK, 0, stream>>>(bnd_raw, flag, net, area, mc,
                                                      (float*)d_out, n_nodes);
}

// Round 13
// 486.319 us; speedup vs baseline: 1.1286x; 1.0959x over previous
//
#include <hip/hip_runtime.h>
#include <cstdint>

// ---- physics constants (match reference) ----
#define WATER_DENSITY 1000.0f
#define ICE_DENSITY 917.0f
#define GRAVITY 9.81f
#define TILL_FRICTION 0.6f
#define LATENT_HEAT 3.34e5f
#define ICE_FLUIDITY 6e-24f
#define WATER_VISCOSITY 1.787e-3f
#define FLOW_REGIME_SCALAR 1e-3f
#define MIN_EFFECTIVE_PRESSURE 1e4f

// Packed u64 accumulator for (degree, sum of u_slide):
//   bits 48..63 : link-endpoint count
//   bits  0..47 : sum of (round(u * 2^46) + 2^40) per endpoint
#define U_SCALE      7.0368744177664e13f     /* 2^46 */
#define U_INV_SCALE  1.4210854715202004e-14f /* 2^-46 */
#define U_BIAS       (1LL << 40)
#define CNT_ONE      (1ULL << 48)
#define LOW_MASK     0xFFFFFFFFFFFFULL

__device__ __forceinline__ bool load_bnd(const uint8_t* p, int i, int is_u8) {
    if (is_u8) return p[i] != 0;
    return ((const int*)p)[i] != 0;
}

// Separate, fully-parallel boundary-encoding detect over the first 64 KB.
// One byte per thread, no loop => no serial tail (r9/r10 regression lesson:
// folding this as a serial scan into link_accum's block 0 cost ~65us).
// Nonzero byte at offset %4 != 0 => byte-wise bool (int32 0/1 LE is nonzero
// only at %4==0). ~2450 expected hits at 5% density => detection certain.
__global__ void detect_bool_width_kernel(const uint8_t* __restrict__ p,
                                         int n_scan,
                                         int* __restrict__ flag_u8) {
    int j = blockIdx.x * blockDim.x + threadIdx.x;
    if (j < n_scan && (j & 3) != 0 && p[j] != 0)
        *flag_u8 = 1;  // racing stores of same value: benign
}

// Pass 1: per-link, ONE packed u64 atomic per endpoint (count + u fixed-point).
// Capped grid-stride: ~4 links/thread, 8 atomics in flight per wave.
__global__ void link_accum_kernel(const int* __restrict__ tail,
                                  const int* __restrict__ head,
                                  const float* __restrict__ u,
                                  unsigned long long* __restrict__ pack,
                                  int n_links) {
    int i = blockIdx.x * blockDim.x + threadIdx.x;
    int stride = gridDim.x * blockDim.x;
    for (; i < n_links; i += stride) {
        int t = tail[i];
        int h = head[i];
        long long fixed = llrintf(u[i] * U_SCALE);
        unsigned long long c = CNT_ONE + (unsigned long long)(fixed + U_BIAS);
        atomicAdd(&pack[t], c);
        atomicAdd(&pack[h], c);
    }
}

// Pass 2: per-node midpoint math. Reads pack[i] (u64) and writes hc[i]
// (float2 {h, conduit}) — same 8-byte slot, element-wise read-then-write
// within one thread, so the aliasing is safe. Also writes mc.
__global__ void node_mid_kernel(const float* __restrict__ head_in,
                                const float* __restrict__ bedrock,
                                const float* __restrict__ overburden,
                                const float* __restrict__ geo,
                                const uint8_t* __restrict__ bnd_raw,
                                const int* __restrict__ flag_u8,
                                unsigned long long* pack_hc,  // no restrict: aliased
                                float* __restrict__ mc_out,
                                int n_nodes) {
    const int is_u8 = *flag_u8;
    float2* hc = (float2*)pack_hc;
    int i = blockIdx.x * blockDim.x + threadIdx.x;
    int stride = gridDim.x * blockDim.x;
    for (; i < n_nodes; i += stride) {
        float bed = bedrock[i];
        float ob  = overburden[i];
        float h   = load_bnd(bnd_raw, i, is_u8) ? bed : head_in[i];

        float wp = WATER_DENSITY * GRAVITY * (h - bed);
        float N  = ob - wp;
        N = (N > ob) ? ob : N;
        N = (N < MIN_EFFECTIVE_PRESSURE) ? MIN_EFFECTIVE_PRESSURE : N;

        unsigned long long v = pack_hc[i];
        long long cnt_i = (long long)(v >> 48);
        long long sumfix = (long long)(v & LOW_MASK) - cnt_i * U_BIAS;
        float u_sum = (float)sumfix * U_INV_SCALE;
        float d = (float)cnt_i;
        d = (d > 1.0f) ? d : 1.0f;
        float u_node = u_sum / d;

        float friction  = fabsf(u_node * (TILL_FRICTION * N));
        float melt_flux = (geo[i] + friction) / LATENT_HEAT;

        float N3 = N * N * N;
        float conduit = melt_flux / ICE_DENSITY / (ICE_FLUIDITY * N3);

        float melt_term    = melt_flux * (1.0f / WATER_DENSITY - 1.0f / ICE_DENSITY);
        float closure_term = ICE_FLUIDITY * N3 * conduit;

        hc[i]     = make_float2(h, conduit);
        mc_out[i] = melt_term + closure_term;
    }
}

// Pass 3: per-link flux. ONE float2 gather per endpoint, scatter signed flux.
__global__ void link_flux_kernel(const int* __restrict__ tail,
                                 const int* __restrict__ head,
                                 const float* __restrict__ len,
                                 const float* __restrict__ Re,
                                 const float2* __restrict__ hc,
                                 float* __restrict__ net,
                                 int n_links) {
    int i = blockIdx.x * blockDim.x + threadIdx.x;
    int stride = gridDim.x * blockDim.x;
    for (; i < n_links; i += stride) {
        int t  = tail[i];
        int hd = head[i];
        float L = len[i];
        float2 a = hc[t];
        float2 b = hc[hd];
        float grad = (b.x - a.x) / L;
        float cl = 0.5f * (a.y + b.y);
        float trans = (cl * cl * cl) * GRAVITY /
                      (12.0f * WATER_VISCOSITY * (1.0f + FLOW_REGIME_SCALAR * Re[i]));
        float flux = -trans * grad * L;
        atomicAdd(&net[t], flux);
        atomicAdd(&net[hd], -flux);
    }
}

// Pass 4: finalize output.
__global__ void node_final_kernel(const uint8_t* __restrict__ bnd_raw,
                                  const int* __restrict__ flag_u8,
                                  const float* __restrict__ net,
                                  const float* __restrict__ area,
                                  const float* __restrict__ mc,
                                  float* __restrict__ out,
                                  int n_nodes) {
    const int is_u8 = *flag_u8;
    int i = blockIdx.x * blockDim.x + threadIdx.x;
    int stride = gridDim.x * blockDim.x;
    for (; i < n_nodes; i += stride) {
        float elliptic = load_bnd(bnd_raw, i, is_u8) ? 0.0f : (net[i] / area[i]);
        out[i] = elliptic - mc[i];
    }
}

extern "C" void kernel_launch(void* const* d_in, const int* in_sizes, int n_in,
                              void* d_out, int out_size, void* d_ws, size_t ws_size,
                              hipStream_t stream) {
    const float*   head_in    = (const float*)d_in[0];
    const float*   Re         = (const float*)d_in[1];
    const float*   len        = (const float*)d_in[2];
    const float*   area       = (const float*)d_in[3];
    const float*   bedrock    = (const float*)d_in[4];
    const float*   overburden = (const float*)d_in[5];
    const float*   geo        = (const float*)d_in[6];
    const float*   u_slide    = (const float*)d_in[7];
    const int*     link_tail  = (const int*)d_in[8];
    const int*     link_head  = (const int*)d_in[9];
    const uint8_t* bnd_raw    = (const uint8_t*)d_in[10];

    const int n_nodes = in_sizes[0];
    const int n_links = in_sizes[1];

    // layout (float units): [pack/hc: 2n (u64 then float2, aliased) | net: n |
    //                        flag: 1 (+pad 256) | mc: n]  => ~16 MB total
    float* ws = (float*)d_ws;
    unsigned long long* pack = (unsigned long long*)ws;
    float2* hc     = (float2*)ws;
    float* net     = ws + 2 * (size_t)n_nodes;
    int*   flag    = (int*)(ws + 3 * (size_t)n_nodes);
    float* mc      = ws + 3 * (size_t)n_nodes + 256;

    // zero pack + net + flag in one contiguous async memset
    hipMemsetAsync(pack, 0, (3 * (size_t)n_nodes + 256) * sizeof(float), stream);

    const int BLK = 256;
    int grid_links = (n_links + BLK - 1) / BLK;
    if (grid_links > 2048) grid_links = 2048;   // grid-stride: ~4 links/thread
    int grid_nodes = (n_nodes + BLK - 1) / BLK;
    if (grid_nodes > 2048) grid_nodes = 2048;   // grid-stride: ~2 nodes/thread
    int n_scan = n_nodes < 65536 ? n_nodes : 65536;
    int grid_scan = (n_scan + BLK - 1) / BLK;   // 1 byte/thread, no serial tail

    detect_bool_width_kernel<<<grid_scan, BLK, 0, stream>>>(bnd_raw, n_scan, flag);
    link_accum_kernel<<<grid_links, BLK, 0, stream>>>(link_tail, link_head, u_slide,
                                                      pack, n_links);
    node_mid_kernel<<<grid_nodes, BLK, 0, stream>>>(head_in, bedrock, overburden, geo,
                                                    bnd_raw, flag, pack, mc, n_nodes);
    link_flux_kernel<<<grid_links, BLK, 0, stream>>>(link_tail, link_head, len, Re,
                                                     hc, net, n_links);
    node_final_kernel<<<grid_nodes, BLK, 0, stream>>>(bnd_raw, flag, net, area, mc,
                                                      (float*)d_out, n_nodes);
}